// Round 2
// baseline (247.794 us; speedup 1.0000x reference)
//
#include <hip/hip_runtime.h>

typedef unsigned short u16;
typedef unsigned int   u32;
typedef __attribute__((ext_vector_type(8)))  short short8;
typedef __attribute__((ext_vector_type(4)))  float f32x4;
typedef __attribute__((ext_vector_type(16))) float f32x16;
typedef __attribute__((ext_vector_type(2)))  u32 uint2v;
typedef __attribute__((ext_vector_type(4)))  u32 uint4v;

#define DEV __device__ __forceinline__

DEV u16 f2bf(float f) {
    u32 u = __builtin_bit_cast(u32, f);
    return (u16)((u + 0x7fffu + ((u >> 16) & 1u)) >> 16);
}
DEV u32 cvtpk(float a, float b) {
    u32 r;
    asm("v_cvt_pk_bf16_f32 %0, %1, %2" : "=v"(r) : "v"(a), "v"(b));
    return r;
}
typedef const __attribute__((address_space(1))) u32 g_u32;
typedef __attribute__((address_space(3))) u32 l_u32;
DEV void gload16(const u16* g, u16* l) {
    __builtin_amdgcn_global_load_lds((g_u32*)g, (l_u32*)l, 16, 0, 0);
}

// ---------------------------------------------------------------------------
// GEMM: C[4096,1024] = A[4096,1024] @ W[1024,1024] + bias, B pre-transposed
// Wt[n][k] bf16. 128x128 tile, BK=32, 256 thr (4 waves, 2x2), 16x16x32 MFMA.
// AMODE: 1 = A f32 (convert in staging)
//        2 = A = (O0+O1) * 1/(l0+l1)  (attention partial combine, f32 in)
// OMODE: 0 = bf16 row-major, 1 = bf16 transposed [bh][d][t] (for V), 2 = f32
// ---------------------------------------------------------------------------
template<int AMODE, int OMODE>
DEV void gemm_body(const void* A_, const void* A2_, const float* __restrict__ L_,
                   const u16* __restrict__ Bt, const float* __restrict__ bias, void* C_) {
    constexpr int Kd = 1024;
    const int m0 = blockIdx.y * 128, n0 = blockIdx.x * 128;
    const int t = threadIdx.x, lane = t & 63, w = t >> 6;
    const int wm = w >> 1, wn = w & 1;
    const int l15 = lane & 15, l4 = lane >> 4;
    __shared__ __align__(16) u16 As[128 * 32];
    __shared__ __align__(16) u16 Bs[128 * 32];
    f32x4 acc[4][4] = {};

    for (int k0 = 0; k0 < Kd; k0 += 32) {
        // stage B (bf16, linear dest = global_load_lds)
        #pragma unroll
        for (int rnd = 0; rnd < 2; rnd++) {
            int cc = rnd * 256 + t, row = cc >> 2, slot = cc & 3;
            gload16(Bt + (size_t)(n0 + row) * Kd + k0 + slot * 8, Bs + cc * 8);
        }
        // stage A
        if (AMODE == 1) {
            const float* Af = (const float*)A_;
            #pragma unroll
            for (int rnd = 0; rnd < 4; rnd++) {
                int row = (t >> 3) + rnd * 32, c4 = (t & 7) * 4;
                float4 vv = *(const float4*)(Af + (size_t)(m0 + row) * Kd + k0 + c4);
                uint2v pp;
                pp[0] = cvtpk(vv.x, vv.y);
                pp[1] = cvtpk(vv.z, vv.w);
                *(uint2v*)(As + row * 32 + c4) = pp;
            }
        } else {
            const float* P0 = (const float*)A_;
            const float* P1 = (const float*)A2_;
            #pragma unroll
            for (int rnd = 0; rnd < 4; rnd++) {
                int row = (t >> 3) + rnd * 32, c4 = (t & 7) * 4;
                size_t gi = (size_t)(m0 + row) * Kd + k0 + c4;
                float4 a  = *(const float4*)(P0 + gi);
                float4 bb = *(const float4*)(P1 + gi);
                int hh = (k0 + c4) >> 6;
                float l0 = L_[(size_t)(m0 + row) * 16 + hh];
                float l1 = L_[65536 + (size_t)(m0 + row) * 16 + hh];
                float rinv = 1.0f / (l0 + l1);
                uint2v pp;
                pp[0] = cvtpk((a.x + bb.x) * rinv, (a.y + bb.y) * rinv);
                pp[1] = cvtpk((a.z + bb.z) * rinv, (a.w + bb.w) * rinv);
                *(uint2v*)(As + row * 32 + c4) = pp;
            }
        }
        __syncthreads();
        short8 af[4], bfr[4];
        #pragma unroll
        for (int i = 0; i < 4; i++) {
            af[i]  = *(const short8*)(As + (wm * 64 + i * 16 + l15) * 32 + l4 * 8);
            bfr[i] = *(const short8*)(Bs + (wn * 64 + i * 16 + l15) * 32 + l4 * 8);
        }
        #pragma unroll
        for (int i = 0; i < 4; i++)
            #pragma unroll
            for (int j = 0; j < 4; j++)
                acc[i][j] = __builtin_amdgcn_mfma_f32_16x16x32_bf16(af[i], bfr[j], acc[i][j], 0, 0, 0);
        __syncthreads();
    }

    #pragma unroll
    for (int i = 0; i < 4; i++) {
        #pragma unroll
        for (int j = 0; j < 4; j++) {
            int col = n0 + wn * 64 + j * 16 + l15;
            int mb  = m0 + wm * 64 + i * 16 + l4 * 4;
            float bv = bias[col];
            if (OMODE == 2) {
                float* C = (float*)C_;
                #pragma unroll
                for (int r = 0; r < 4; r++)
                    C[(size_t)(mb + r) * 1024 + col] = acc[i][j][r] + bv;
            } else if (OMODE == 0) {
                u16* C = (u16*)C_;
                #pragma unroll
                for (int r = 0; r < 4; r++)
                    C[(size_t)(mb + r) * 1024 + col] = f2bf(acc[i][j][r] + bv);
            } else {
                // V: write transposed [bh][d][t], 4 consecutive tokens packed
                u16* C = (u16*)C_;
                int hh = col >> 6, dd = col & 63;
                int bb = mb >> 11, tt = mb & 2047;
                uint2v pp;
                pp[0] = cvtpk(acc[i][j][0] + bv, acc[i][j][1] + bv);
                pp[1] = cvtpk(acc[i][j][2] + bv, acc[i][j][3] + bv);
                *(uint2v*)(C + ((size_t)((bb * 16 + hh) * 64 + dd)) * 2048 + tt) = pp;
            }
        }
    }
}

// weights: W[k][n] f32 -> Wt[n][k] bf16
__global__ __launch_bounds__(256) void k_transw(const float* Wq, const float* Wk,
                                                const float* Wv, const float* Wo, u16* Wt) {
    int z = blockIdx.z;
    const float* W = z == 0 ? Wq : z == 1 ? Wk : z == 2 ? Wv : Wo;
    u16* O = Wt + (size_t)z * 1048576;
    __shared__ float tile[32][33];
    int n0 = blockIdx.x * 32, k0 = blockIdx.y * 32;
    int tx = threadIdx.x, ty = threadIdx.y;
    #pragma unroll
    for (int i = 0; i < 32; i += 8) tile[ty + i][tx] = W[(size_t)(k0 + ty + i) * 1024 + n0 + tx];
    __syncthreads();
    #pragma unroll
    for (int i = 0; i < 32; i += 8) O[(size_t)(n0 + ty + i) * 1024 + k0 + tx] = f2bf(tile[tx][ty + i]);
}

__global__ __launch_bounds__(256) void k_proj(const float* q, const float* k, const float* v,
                                              const u16* Wt, const float* bq, const float* bk,
                                              const float* bv, u16* QKV) {
    int z = blockIdx.z;
    if (z == 2)      gemm_body<1, 1>(v, nullptr, nullptr, Wt + (size_t)2 * 1048576, bv, QKV + (size_t)2 * 4194304);
    else if (z == 1) gemm_body<1, 0>(k, nullptr, nullptr, Wt + (size_t)1 * 1048576, bk, QKV + (size_t)1 * 4194304);
    else             gemm_body<1, 0>(q, nullptr, nullptr, Wt, bq, QKV);
}

__global__ __launch_bounds__(256) void k_gemm_out(const float* P0, const float* Lp, const u16* Wt,
                                                  const float* bo, float* out) {
    gemm_body<2, 2>(P0, P0 + (size_t)4194304, Lp, Wt, bo, out);
}

// ---------------------------------------------------------------------------
// Causal flash attention, no-max softmax, K-SPLIT x2 (grid.z), heavy-first x.
// grid (T/128, B*H, 2), 256 thr. Each wave owns 32 q rows, half the k-range.
// Swapped QK^T: S^T = mfma(K,Q) so each lane owns one q-row's P slice.
// Software pipeline: parity-unrolled x2 with double-buffered K/V fragments.
// Partials: O (f32, [split][B*T][D]) + lsum ([split][B*T][H]); combine fused
// into the output GEMM's A-staging (no-max softmax => partials just add).
// ---------------------------------------------------------------------------
__global__ __launch_bounds__(256, 3) void k_attn(const u16* __restrict__ Qp, const u16* __restrict__ Kp,
                                                 const u16* __restrict__ VT,
                                                 float* __restrict__ Op, float* __restrict__ Lp) {
    const int bh = blockIdx.y, b = bh >> 4, h = bh & 15;
    const int t = threadIdx.x, lane = t & 63, w = t >> 6;
    const int lo = lane & 31, hi = lane >> 5;
    const int split = blockIdx.z;
    const int q0w = (int)(gridDim.x - 1 - blockIdx.x) * 128 + w * 32;   // heavy-first
    const u16* Qb = Qp + (size_t)(b * 2048) * 1024 + h * 64;
    const u16* Kb = Kp + (size_t)(b * 2048) * 1024 + h * 64;
    const u16* Vb = VT + (size_t)(bh * 64) * 2048;

    short8 qf[4];
    #pragma unroll
    for (int c = 0; c < 4; c++)
        qf[c] = *(const short8*)(Qb + (size_t)(q0w + lo) * 1024 + c * 16 + hi * 8);

    f32x16 O0 = {}, O1 = {};
    float lsum = 0.f;
    const int qg = q0w + lo;
    const int nk = (q0w >> 5) + 1;       // causal k-tiles for this wave
    const int c0 = (nk + 1) >> 1;        // split 0 takes first c0 tiles
    const int kbeg = split ? (c0 << 5) : 0;
    const int kend = split ? (nk << 5) : (c0 << 5);

#define LOADKV(KF, VF, kk) do {                                                          \
        _Pragma("unroll")                                                                \
        for (int c = 0; c < 4; c++)                                                      \
            KF[c] = *(const short8*)(Kb + (size_t)((kk) + lo) * 1024 + c * 16 + hi * 8); \
        _Pragma("unroll")                                                                \
        for (int i = 0; i < 4; i++)                                                      \
            VF[i] = *(const short8*)(Vb + (size_t)((i >> 1) * 32 + lo) * 2048            \
                                     + (kk) + (i & 1) * 16 + hi * 8);                    \
    } while (0)

#define COMPUTE(KF, VF, kk) do {                                                          \
        f32x16 S = {};                                                                    \
        _Pragma("unroll")                                                                 \
        for (int c = 0; c < 4; c++)                                                       \
            S = __builtin_amdgcn_mfma_f32_32x32x16_bf16(KF[c], qf[c], S, 0, 0, 0);        \
        const bool diag = ((kk) == q0w);                                                  \
        _Pragma("unroll")                                                                 \
        for (int kc = 0; kc < 2; kc++) {                                                  \
            float p[8];                                                                   \
            _Pragma("unroll")                                                             \
            for (int j = 0; j < 8; j++) {                                                 \
                int r = kc * 8 + j;                                                       \
                float s = S[r] * 0.125f;                                                  \
                if (diag) {                                                               \
                    int kg = (kk) + (r & 3) + 8 * (r >> 2) + 4 * hi;                      \
                    s = (kg <= qg) ? s : -1e30f;                                          \
                }                                                                         \
                p[j] = __expf(s); lsum += p[j];                                           \
            }                                                                             \
            u32 w0 = cvtpk(p[0], p[1]), w1 = cvtpk(p[2], p[3]);                           \
            u32 w2 = cvtpk(p[4], p[5]), w3 = cvtpk(p[6], p[7]);                           \
            auto r0 = __builtin_amdgcn_permlane32_swap(w0, w2, false, false);             \
            auto r1 = __builtin_amdgcn_permlane32_swap(w1, w3, false, false);             \
            uint4v fw; fw[0] = r0[0]; fw[1] = r1[0]; fw[2] = r0[1]; fw[3] = r1[1];        \
            short8 pf = __builtin_bit_cast(short8, fw);                                   \
            O0 = __builtin_amdgcn_mfma_f32_32x32x16_bf16(pf, VF[0 + kc], O0, 0, 0, 0);    \
            O1 = __builtin_amdgcn_mfma_f32_32x32x16_bf16(pf, VF[2 + kc], O1, 0, 0, 0);    \
        }                                                                                 \
    } while (0)

    if (kbeg < kend) {
        short8 kf0[4], vf0[4], kf1[4], vf1[4];
        LOADKV(kf0, vf0, kbeg);
        int k0 = kbeg;
        while (true) {
            if (k0 + 32 < kend) LOADKV(kf1, vf1, k0 + 32);
            COMPUTE(kf0, vf0, k0);
            k0 += 32;
            if (k0 >= kend) break;
            if (k0 + 32 < kend) LOADKV(kf0, vf0, k0 + 32);
            COMPUTE(kf1, vf1, k0);
            k0 += 32;
            if (k0 >= kend) break;
        }
    }
#undef LOADKV
#undef COMPUTE

    float ltot = lsum + __shfl_xor(lsum, 32, 64);
    float* Ob = Op + (size_t)split * 4194304;
    #pragma unroll
    for (int r = 0; r < 16; r++) {
        int qr = (r & 3) + 8 * (r >> 2) + 4 * hi;
        size_t rowb = (size_t)(b * 2048 + q0w + qr) * 1024 + h * 64;
        Ob[rowb + lo]      = O0[r];
        Ob[rowb + 32 + lo] = O1[r];
    }
    if (hi == 0)
        Lp[(size_t)split * 65536 + (size_t)(b * 2048 + q0w + lo) * 16 + h] = ltot;
}

extern "C" void kernel_launch(void* const* d_in, const int* in_sizes, int n_in,
                              void* d_out, int out_size, void* d_ws, size_t ws_size,
                              hipStream_t stream) {
    (void)in_sizes; (void)n_in; (void)out_size; (void)ws_size;
    const float* q  = (const float*)d_in[0];
    const float* k  = (const float*)d_in[1];
    const float* v  = (const float*)d_in[2];
    const float* Wq = (const float*)d_in[3];
    const float* bq = (const float*)d_in[4];
    const float* Wk = (const float*)d_in[5];
    const float* bk = (const float*)d_in[6];
    const float* Wv = (const float*)d_in[7];
    const float* bv = (const float*)d_in[8];
    const float* Wo = (const float*)d_in[9];
    const float* bo = (const float*)d_in[10];

    u16*   Wt    = (u16*)d_ws;                        // 4 x 1024x1024 bf16 (8 MB)
    u16*   QKV   = Wt + (size_t)4 * 1048576;          // 3 x 4096x1024 bf16 (24 MB)
    float* Opart = (float*)(QKV + (size_t)3 * 4194304); // 2 x 4096x1024 f32 (32 MB)
    float* Lp    = Opart + (size_t)2 * 4194304;       // 2 x 4096x16 f32 (512 KB)

    k_transw<<<dim3(32, 32, 4), dim3(32, 8), 0, stream>>>(Wq, Wk, Wv, Wo, Wt);
    k_proj<<<dim3(8, 32, 3), 256, 0, stream>>>(q, k, v, Wt, bq, bk, bv, QKV);
    k_attn<<<dim3(16, 32, 2), 256, 0, stream>>>(QKV, QKV + (size_t)4194304,
                                                QKV + (size_t)2 * 4194304, Opart, Lp);
    k_gemm_out<<<dim3(8, 32), 256, 0, stream>>>(Opart, Lp, Wt + (size_t)3 * 1048576,
                                                bo, (float*)d_out);
}

// Round 4
// 168.168 us; speedup vs baseline: 1.4735x; 1.4735x over previous
//
#include <hip/hip_runtime.h>

typedef unsigned short u16;
typedef unsigned int   u32;
typedef __attribute__((ext_vector_type(8)))  short short8;
typedef __attribute__((ext_vector_type(4)))  float f32x4;
typedef __attribute__((ext_vector_type(16))) float f32x16;
typedef __attribute__((ext_vector_type(2)))  u32 uint2v;
typedef __attribute__((ext_vector_type(4)))  u32 uint4v;

#define DEV __device__ __forceinline__

DEV u16 f2bf(float f) {
    u32 u = __builtin_bit_cast(u32, f);
    return (u16)((u + 0x7fffu + ((u >> 16) & 1u)) >> 16);
}
DEV float bf2f(u32 u) { return __builtin_bit_cast(float, u << 16); }
DEV u32 cvtpk(float a, float b) {
    u32 r;
    asm("v_cvt_pk_bf16_f32 %0, %1, %2" : "=v"(r) : "v"(a), "v"(b));
    return r;
}
typedef const __attribute__((address_space(1))) u32 g_u32;
typedef __attribute__((address_space(3))) u32 l_u32;
DEV void gload16(const u16* g, u16* l) {
    __builtin_amdgcn_global_load_lds((g_u32*)g, (l_u32*)l, 16, 0, 0);
}

// ---------------------------------------------------------------------------
// Packed K layout (per bh, per 32-token tile, 4KB): elem index
//   ((c*2+hi)*32 + lo)*8 + e  holds  K[t=tblk*32+lo][d=c*16+hi*8+e]
// => attn fragment load kf[c] = 16B at tile + (c*64+lane)*16B, fully linear.
// Packed V layout (per bh, per 32-token tile, 4KB): elem index
//   ((kc*2+c2)*64 + hi*32 + lo)*8 + e holds V[t=tblk*32+kc*16+hi*8+e][d=c2*32+lo]
// => attn fragment load vf[kc*2+c2] = 16B at tile + ((kc*2+c2)*64+lane)*16B.
// ---------------------------------------------------------------------------

// GEMM: C[4096,1024] = A[4096,1024] @ W[1024,1024] + bias, Wt[n][k] bf16.
// 128x128 tile, BK=32, 256 thr (4 waves 2x2), 16x16x32 MFMA.
// AMODE 1: A f32 (convert in staging); AMODE 2: weighted combine of two
//   pre-normalized bf16 attention partials: A = x0*l0/(l0+l1) + x1*l1/(l0+l1).
// OMODE 0: bf16 row-major (*oscale); 1: packed-V tiles; 2: f32 row-major;
//   3: packed-K tiles.
template<int AMODE, int OMODE>
DEV void gemm_body(const void* A_, const void* A2_, const float* __restrict__ L_,
                   const u16* __restrict__ Bt, const float* __restrict__ bias,
                   float oscale, void* C_) {
    constexpr int Kd = 1024;
    const int m0 = blockIdx.y * 128, n0 = blockIdx.x * 128;
    const int t = threadIdx.x, lane = t & 63, w = t >> 6;
    const int wm = w >> 1, wn = w & 1;
    const int l15 = lane & 15, l4 = lane >> 4;
    __shared__ __align__(16) u16 As[128 * 32];
    __shared__ __align__(16) u16 Bs[128 * 32];
    f32x4 acc[4][4] = {};

    for (int k0 = 0; k0 < Kd; k0 += 32) {
        #pragma unroll
        for (int rnd = 0; rnd < 2; rnd++) {
            int cc = rnd * 256 + t, row = cc >> 2, slot = cc & 3;
            gload16(Bt + (size_t)(n0 + row) * Kd + k0 + slot * 8, Bs + cc * 8);
        }
        if (AMODE == 1) {
            const float* Af = (const float*)A_;
            #pragma unroll
            for (int rnd = 0; rnd < 4; rnd++) {
                int row = (t >> 3) + rnd * 32, c4 = (t & 7) * 4;
                float4 vv = *(const float4*)(Af + (size_t)(m0 + row) * Kd + k0 + c4);
                uint2v pp;
                pp[0] = cvtpk(vv.x, vv.y);
                pp[1] = cvtpk(vv.z, vv.w);
                *(uint2v*)(As + row * 32 + c4) = pp;
            }
        } else {
            const u16* X0 = (const u16*)A_;
            const u16* X1 = (const u16*)A2_;
            #pragma unroll
            for (int rnd = 0; rnd < 4; rnd++) {
                int row = (t >> 3) + rnd * 32, c4 = (t & 7) * 4;
                size_t gi = (size_t)(m0 + row) * Kd + k0 + c4;
                uint2v x0 = *(const uint2v*)(X0 + gi);
                uint2v x1 = *(const uint2v*)(X1 + gi);
                int hh = (k0 + c4) >> 6;
                float l0 = L_[(size_t)(m0 + row) * 16 + hh];
                float l1 = L_[65536 + (size_t)(m0 + row) * 16 + hh];
                float s = 1.0f / (l0 + l1);
                float w0 = l0 * s, w1 = l1 * s;
                float a0 = bf2f(x0[0] & 0xffffu) * w0 + bf2f(x1[0] & 0xffffu) * w1;
                float a1 = bf2f(x0[0] >> 16)    * w0 + bf2f(x1[0] >> 16)    * w1;
                float a2 = bf2f(x0[1] & 0xffffu) * w0 + bf2f(x1[1] & 0xffffu) * w1;
                float a3 = bf2f(x0[1] >> 16)    * w0 + bf2f(x1[1] >> 16)    * w1;
                uint2v pp;
                pp[0] = cvtpk(a0, a1);
                pp[1] = cvtpk(a2, a3);
                *(uint2v*)(As + row * 32 + c4) = pp;
            }
        }
        __syncthreads();
        short8 af[4], bfr[4];
        #pragma unroll
        for (int i = 0; i < 4; i++) {
            af[i]  = *(const short8*)(As + (wm * 64 + i * 16 + l15) * 32 + l4 * 8);
            bfr[i] = *(const short8*)(Bs + (wn * 64 + i * 16 + l15) * 32 + l4 * 8);
        }
        #pragma unroll
        for (int i = 0; i < 4; i++)
            #pragma unroll
            for (int j = 0; j < 4; j++)
                acc[i][j] = __builtin_amdgcn_mfma_f32_16x16x32_bf16(af[i], bfr[j], acc[i][j], 0, 0, 0);
        __syncthreads();
    }

    #pragma unroll
    for (int i = 0; i < 4; i++) {
        #pragma unroll
        for (int j = 0; j < 4; j++) {
            int col = n0 + wn * 64 + j * 16 + l15;
            int mb  = m0 + wm * 64 + i * 16 + l4 * 4;
            float bv = bias[col];
            if (OMODE == 2) {
                float* C = (float*)C_;
                #pragma unroll
                for (int r = 0; r < 4; r++)
                    C[(size_t)(mb + r) * 1024 + col] = acc[i][j][r] + bv;
            } else if (OMODE == 0) {
                u16* C = (u16*)C_;
                #pragma unroll
                for (int r = 0; r < 4; r++)
                    C[(size_t)(mb + r) * 1024 + col] = f2bf((acc[i][j][r] + bv) * oscale);
            } else if (OMODE == 3) {
                // packed K tiles
                u16* C = (u16*)C_;
                int hh = col >> 6, dd = col & 63;
                int bb = mb >> 11, tt = mb & 2047;
                size_t tile = ((size_t)(bb * 16 + hh) * 64 + (tt >> 5)) * 2048;
                int c = dd >> 4, hi2 = (dd >> 3) & 1, e = dd & 7;
                int lob = tt & 31;
                #pragma unroll
                for (int r = 0; r < 4; r++)
                    C[tile + (size_t)((c * 2 + hi2) * 32 + lob + r) * 8 + e] =
                        f2bf(acc[i][j][r] + bv);
            } else {
                // packed V tiles: 4 consecutive tokens are contiguous elems
                u16* C = (u16*)C_;
                int hh = col >> 6, dd = col & 63;
                int bb = mb >> 11, tt = mb & 2047;
                size_t tile = ((size_t)(bb * 16 + hh) * 64 + (tt >> 5)) * 2048;
                int tin = tt & 31, kc = tin >> 4, hi2 = (tin >> 3) & 1, e0 = tin & 7;
                int c2 = dd >> 5, lo2 = dd & 31;
                size_t off = tile + (size_t)((kc * 2 + c2) * 64 + hi2 * 32 + lo2) * 8 + e0;
                uint2v pp;
                pp[0] = cvtpk(acc[i][j][0] + bv, acc[i][j][1] + bv);
                pp[1] = cvtpk(acc[i][j][2] + bv, acc[i][j][3] + bv);
                *(uint2v*)(C + off) = pp;
            }
        }
    }
}

// weights: W[k][n] f32 -> Wt[n][k] bf16
__global__ __launch_bounds__(256) void k_transw(const float* Wq, const float* Wk,
                                                const float* Wv, const float* Wo, u16* Wt) {
    int z = blockIdx.z;
    const float* W = z == 0 ? Wq : z == 1 ? Wk : z == 2 ? Wv : Wo;
    u16* O = Wt + (size_t)z * 1048576;
    __shared__ float tile[32][33];
    int n0 = blockIdx.x * 32, k0 = blockIdx.y * 32;
    int tx = threadIdx.x, ty = threadIdx.y;
    #pragma unroll
    for (int i = 0; i < 32; i += 8) tile[ty + i][tx] = W[(size_t)(k0 + ty + i) * 1024 + n0 + tx];
    __syncthreads();
    #pragma unroll
    for (int i = 0; i < 32; i += 8) O[(size_t)(n0 + ty + i) * 1024 + k0 + tx] = f2bf(tile[tx][ty + i]);
}

__global__ __launch_bounds__(256) void k_proj(const float* q, const float* k, const float* v,
                                              const u16* Wt, const float* bq, const float* bk,
                                              const float* bv, u16* QKV) {
    int z = blockIdx.z;
    if (z == 2)
        gemm_body<1, 1>(v, nullptr, nullptr, Wt + (size_t)2 * 1048576, bv, 1.f,
                        QKV + (size_t)2 * 4194304);
    else if (z == 1)
        gemm_body<1, 3>(k, nullptr, nullptr, Wt + (size_t)1 * 1048576, bk, 1.f,
                        QKV + (size_t)1 * 4194304);
    else
        gemm_body<1, 0>(q, nullptr, nullptr, Wt, bq, 0.125f, QKV);  // softmax scale folded
}

__global__ __launch_bounds__(256) void k_gemm_out(const u16* Xp, const float* Lp, const u16* Wt,
                                                  const float* bo, float* out) {
    gemm_body<2, 2>(Xp, Xp + (size_t)4194304, Lp, Wt, bo, 1.f, out);
}

// ---------------------------------------------------------------------------
// Causal flash attention, no-max softmax, K-split x2, heavy-first.
// grid (16, 32, 2), 256 thr; each wave owns 32 q rows, half the k-range.
// All K/V fragment loads are 1KB fully-coalesced reads from packed tiles.
// Partials: pre-normalized bf16 O + f32 lsum; combine fused in output GEMM.
// ---------------------------------------------------------------------------
__global__ __launch_bounds__(256, 3) void k_attn(const u16* __restrict__ Qp,
                                                 const u16* __restrict__ Kp2,
                                                 const u16* __restrict__ Vp2,
                                                 u16* __restrict__ Xp, float* __restrict__ Lp) {
    const int bh = blockIdx.y, b = bh >> 4, h = bh & 15;
    const int t = threadIdx.x, lane = t & 63, w = t >> 6;
    const int lo = lane & 31, hi = lane >> 5;
    const int split = blockIdx.z;
    const int q0w = (int)(gridDim.x - 1 - blockIdx.x) * 128 + w * 32;   // heavy-first
    const u16* Qb = Qp + (size_t)(b * 2048) * 1024 + h * 64;
    const u16* Kb = Kp2 + (size_t)bh * 64 * 2048;
    const u16* Vb = Vp2 + (size_t)bh * 64 * 2048;

    short8 qf[4];
    #pragma unroll
    for (int c = 0; c < 4; c++)
        qf[c] = *(const short8*)(Qb + (size_t)(q0w + lo) * 1024 + c * 16 + hi * 8);

    f32x16 O0 = {}, O1 = {};
    float lsum = 0.f;
    const int qg = q0w + lo;
    const int nk = (q0w >> 5) + 1;       // causal k-tiles for this wave
    const int c0 = (nk + 1) >> 1;        // split 0 takes first c0 tiles
    const int kbeg = split ? (c0 << 5) : 0;
    const int kend = split ? (nk << 5) : (c0 << 5);

#define LOADKV(KF, VF, kk) do {                                                          \
        const u16* kt_ = Kb + (size_t)((kk) >> 5) * 2048;                                \
        const u16* vt_ = Vb + (size_t)((kk) >> 5) * 2048;                                \
        _Pragma("unroll")                                                                \
        for (int c = 0; c < 4; c++)                                                      \
            KF[c] = *(const short8*)(kt_ + c * 512 + lane * 8);                          \
        _Pragma("unroll")                                                                \
        for (int j = 0; j < 4; j++)                                                      \
            VF[j] = *(const short8*)(vt_ + j * 512 + lane * 8);                          \
    } while (0)

#define COMPUTE(KF, VF, kk) do {                                                          \
        f32x16 S = {};                                                                    \
        _Pragma("unroll")                                                                 \
        for (int c = 0; c < 4; c++)                                                       \
            S = __builtin_amdgcn_mfma_f32_32x32x16_bf16(KF[c], qf[c], S, 0, 0, 0);        \
        const bool diag = ((kk) == q0w);                                                  \
        _Pragma("unroll")                                                                 \
        for (int kc = 0; kc < 2; kc++) {                                                  \
            float p[8];                                                                   \
            _Pragma("unroll")                                                             \
            for (int j = 0; j < 8; j++) {                                                 \
                int r = kc * 8 + j;                                                       \
                float s = S[r];                                                           \
                if (diag) {                                                               \
                    int kg = (kk) + (r & 3) + 8 * (r >> 2) + 4 * hi;                      \
                    s = (kg <= qg) ? s : -1e30f;                                          \
                }                                                                         \
                p[j] = __expf(s);                                                         \
            }                                                                             \
            lsum += (((p[0] + p[1]) + (p[2] + p[3])) + ((p[4] + p[5]) + (p[6] + p[7])));  \
            u32 w0 = cvtpk(p[0], p[1]), w1 = cvtpk(p[2], p[3]);                           \
            u32 w2 = cvtpk(p[4], p[5]), w3 = cvtpk(p[6], p[7]);                           \
            auto r0 = __builtin_amdgcn_permlane32_swap(w0, w2, false, false);             \
            auto r1 = __builtin_amdgcn_permlane32_swap(w1, w3, false, false);             \
            uint4v fw; fw[0] = r0[0]; fw[1] = r1[0]; fw[2] = r0[1]; fw[3] = r1[1];        \
            short8 pf = __builtin_bit_cast(short8, fw);                                   \
            O0 = __builtin_amdgcn_mfma_f32_32x32x16_bf16(pf, VF[kc * 2 + 0], O0, 0, 0, 0);\
            O1 = __builtin_amdgcn_mfma_f32_32x32x16_bf16(pf, VF[kc * 2 + 1], O1, 0, 0, 0);\
        }                                                                                 \
    } while (0)

    if (kbeg < kend) {
        short8 kf0[4], vf0[4], kf1[4], vf1[4];
        LOADKV(kf0, vf0, kbeg);
        int k0 = kbeg;
        while (true) {
            if (k0 + 32 < kend) LOADKV(kf1, vf1, k0 + 32);
            COMPUTE(kf0, vf0, k0);
            k0 += 32;
            if (k0 >= kend) break;
            if (k0 + 32 < kend) LOADKV(kf0, vf0, k0 + 32);
            COMPUTE(kf1, vf1, k0);
            k0 += 32;
            if (k0 >= kend) break;
        }
    }
#undef LOADKV
#undef COMPUTE

    float ltot = lsum + __shfl_xor(lsum, 32, 64);
    u16* Xb = Xp + (size_t)split * 4194304;
    #pragma unroll
    for (int r = 0; r < 16; r++) {
        int qr = (r & 3) + 8 * (r >> 2) + 4 * hi;
        // normalizer belongs to q-row qr, which lives in lane qr (and qr+32)
        float lt = __shfl(ltot, qr, 64);
        float linv = lt > 0.f ? 1.f / lt : 0.f;
        size_t rowb = (size_t)(b * 2048 + q0w + qr) * 1024 + h * 64;
        Xb[rowb + lo]      = f2bf(O0[r] * linv);
        Xb[rowb + 32 + lo] = f2bf(O1[r] * linv);
    }
    if (hi == 0)
        Lp[(size_t)split * 65536 + (size_t)(b * 2048 + q0w + lo) * 16 + h] = ltot;
}

extern "C" void kernel_launch(void* const* d_in, const int* in_sizes, int n_in,
                              void* d_out, int out_size, void* d_ws, size_t ws_size,
                              hipStream_t stream) {
    (void)in_sizes; (void)n_in; (void)out_size; (void)ws_size;
    const float* q  = (const float*)d_in[0];
    const float* k  = (const float*)d_in[1];
    const float* v  = (const float*)d_in[2];
    const float* Wq = (const float*)d_in[3];
    const float* bq = (const float*)d_in[4];
    const float* Wk = (const float*)d_in[5];
    const float* bk = (const float*)d_in[6];
    const float* Wv = (const float*)d_in[7];
    const float* bv = (const float*)d_in[8];
    const float* Wo = (const float*)d_in[9];
    const float* bo = (const float*)d_in[10];

    u16*   Wt  = (u16*)d_ws;                          // 4 x 1024x1024 bf16 (8 MB)
    u16*   QKV = Wt + (size_t)4 * 1048576;            // Q row-major + K,V packed (24 MB)
    u16*   Xp  = QKV + (size_t)3 * 4194304;           // 2 x 4096x1024 bf16 partials (16 MB)
    float* Lp  = (float*)(Xp + (size_t)2 * 4194304);  // 2 x 4096x16 f32 (512 KB)

    k_transw<<<dim3(32, 32, 4), dim3(32, 8), 0, stream>>>(Wq, Wk, Wv, Wo, Wt);
    k_proj<<<dim3(8, 32, 3), 256, 0, stream>>>(q, k, v, Wt, bq, bk, bv, QKV);
    k_attn<<<dim3(16, 32, 2), 256, 0, stream>>>(QKV, QKV + (size_t)4194304,
                                                QKV + (size_t)2 * 4194304, Xp, Lp);
    k_gemm_out<<<dim3(8, 32), 256, 0, stream>>>(Xp, Lp, Wt + (size_t)3 * 1048576,
                                                bo, (float*)d_out);
}

// Round 5
// 139.370 us; speedup vs baseline: 1.7780x; 1.2066x over previous
//
#include <hip/hip_runtime.h>

typedef unsigned short u16;
typedef unsigned int   u32;
typedef __attribute__((ext_vector_type(8)))  short short8;
typedef __attribute__((ext_vector_type(4)))  float f32x4;
typedef __attribute__((ext_vector_type(16))) float f32x16;
typedef __attribute__((ext_vector_type(2)))  u32 uint2v;
typedef __attribute__((ext_vector_type(4)))  u32 uint4v;

#define DEV __device__ __forceinline__

DEV u16 f2bf(float f) {
    u32 u = __builtin_bit_cast(u32, f);
    return (u16)((u + 0x7fffu + ((u >> 16) & 1u)) >> 16);
}
DEV float bf2f(u32 u) { return __builtin_bit_cast(float, u << 16); }
DEV u32 cvtpk(float a, float b) {
    u32 r;
    asm("v_cvt_pk_bf16_f32 %0, %1, %2" : "=v"(r) : "v"(a), "v"(b));
    return r;
}
typedef const __attribute__((address_space(1))) u32 g_u32;
typedef __attribute__((address_space(3))) u32 l_u32;
DEV void gload16(const u16* g, u16* l) {
    __builtin_amdgcn_global_load_lds((g_u32*)g, (l_u32*)l, 16, 0, 0);
}

// ---------------------------------------------------------------------------
// Packed K layout (per bh, per 32-token tile, 4KB): elem index
//   ((c*2+hi)*32 + lo)*8 + e  holds  K[t=tblk*32+lo][d=c*16+hi*8+e]
// => attn fragment load kf[c] = 16B at tile + (c*64+lane)*16B, fully linear.
// Packed V layout (per bh, per 32-token tile, 4KB): elem index
//   ((kc*2+c2)*64 + hi*32 + lo)*8 + e holds V[t=tblk*32+kc*16+hi*8+e][d=c2*32+lo]
// => attn fragment load vf[kc*2+c2] = 16B at tile + ((kc*2+c2)*64+lane)*16B.
// ---------------------------------------------------------------------------

// GEMM: C[4096,1024] = A[4096,1024](bf16) @ Wt[n][k](bf16) + bias.
// 128x128 tile, BK=32, 256 thr (4 waves 2x2), 16x16x32 MFMA.
// Both A and B staged via global_load_lds width-16 (m97 path).
// OMODE 0: bf16 row-major (*oscale); 1: packed-V tiles; 2: f32 row-major;
//   3: packed-K tiles.
template<int OMODE>
DEV void gemm_body(const u16* __restrict__ A_, const u16* __restrict__ Bt,
                   const float* __restrict__ bias, float oscale, void* C_) {
    constexpr int Kd = 1024;
    const int m0 = blockIdx.y * 128, n0 = blockIdx.x * 128;
    const int t = threadIdx.x, lane = t & 63, w = t >> 6;
    const int wm = w >> 1, wn = w & 1;
    const int l15 = lane & 15, l4 = lane >> 4;
    __shared__ __align__(16) u16 As[128 * 32];
    __shared__ __align__(16) u16 Bs[128 * 32];
    f32x4 acc[4][4] = {};

    for (int k0 = 0; k0 < Kd; k0 += 32) {
        #pragma unroll
        for (int rnd = 0; rnd < 2; rnd++) {
            int cc = rnd * 256 + t, row = cc >> 2, slot = cc & 3;
            gload16(Bt + (size_t)(n0 + row) * Kd + k0 + slot * 8, Bs + cc * 8);
            gload16(A_ + (size_t)(m0 + row) * Kd + k0 + slot * 8, As + cc * 8);
        }
        __syncthreads();
        short8 af[4], bfr[4];
        #pragma unroll
        for (int i = 0; i < 4; i++) {
            af[i]  = *(const short8*)(As + (wm * 64 + i * 16 + l15) * 32 + l4 * 8);
            bfr[i] = *(const short8*)(Bs + (wn * 64 + i * 16 + l15) * 32 + l4 * 8);
        }
        #pragma unroll
        for (int i = 0; i < 4; i++)
            #pragma unroll
            for (int j = 0; j < 4; j++)
                acc[i][j] = __builtin_amdgcn_mfma_f32_16x16x32_bf16(af[i], bfr[j], acc[i][j], 0, 0, 0);
        __syncthreads();
    }

    #pragma unroll
    for (int i = 0; i < 4; i++) {
        #pragma unroll
        for (int j = 0; j < 4; j++) {
            int col = n0 + wn * 64 + j * 16 + l15;
            int mb  = m0 + wm * 64 + i * 16 + l4 * 4;
            float bv = bias[col];
            if (OMODE == 2) {
                float* C = (float*)C_;
                #pragma unroll
                for (int r = 0; r < 4; r++)
                    C[(size_t)(mb + r) * 1024 + col] = acc[i][j][r] + bv;
            } else if (OMODE == 0) {
                u16* C = (u16*)C_;
                #pragma unroll
                for (int r = 0; r < 4; r++)
                    C[(size_t)(mb + r) * 1024 + col] = f2bf((acc[i][j][r] + bv) * oscale);
            } else if (OMODE == 3) {
                // packed K tiles
                u16* C = (u16*)C_;
                int hh = col >> 6, dd = col & 63;
                int bb = mb >> 11, tt = mb & 2047;
                size_t tile = ((size_t)(bb * 16 + hh) * 64 + (tt >> 5)) * 2048;
                int c = dd >> 4, hi2 = (dd >> 3) & 1, e = dd & 7;
                int lob = tt & 31;
                #pragma unroll
                for (int r = 0; r < 4; r++)
                    C[tile + (size_t)((c * 2 + hi2) * 32 + lob + r) * 8 + e] =
                        f2bf(acc[i][j][r] + bv);
            } else {
                // packed V tiles: 4 consecutive tokens are contiguous elems
                u16* C = (u16*)C_;
                int hh = col >> 6, dd = col & 63;
                int bb = mb >> 11, tt = mb & 2047;
                size_t tile = ((size_t)(bb * 16 + hh) * 64 + (tt >> 5)) * 2048;
                int tin = tt & 31, kc = tin >> 4, hi2 = (tin >> 3) & 1, e0 = tin & 7;
                int c2 = dd >> 5, lo2 = dd & 31;
                size_t off = tile + (size_t)((kc * 2 + c2) * 64 + hi2 * 32 + lo2) * 8 + e0;
                uint2v pp;
                pp[0] = cvtpk(acc[i][j][0] + bv, acc[i][j][1] + bv);
                pp[1] = cvtpk(acc[i][j][2] + bv, acc[i][j][3] + bv);
                *(uint2v*)(C + off) = pp;
            }
        }
    }
}

// weights: W[k][n] f32 -> Wt[n][k] bf16
__global__ __launch_bounds__(256) void k_transw(const float* Wq, const float* Wk,
                                                const float* Wv, const float* Wo, u16* Wt) {
    int z = blockIdx.z;
    const float* W = z == 0 ? Wq : z == 1 ? Wk : z == 2 ? Wv : Wo;
    u16* O = Wt + (size_t)z * 1048576;
    __shared__ float tile[32][33];
    int n0 = blockIdx.x * 32, k0 = blockIdx.y * 32;
    int tx = threadIdx.x, ty = threadIdx.y;
    #pragma unroll
    for (int i = 0; i < 32; i += 8) tile[ty + i][tx] = W[(size_t)(k0 + ty + i) * 1024 + n0 + tx];
    __syncthreads();
    #pragma unroll
    for (int i = 0; i < 32; i += 8) O[(size_t)(n0 + ty + i) * 1024 + k0 + tx] = f2bf(tile[tx][ty + i]);
}

// q,k,v f32 -> bf16, fully coalesced, 8 elems/thread, exact coverage
__global__ __launch_bounds__(256) void k_cvt(const float* q, const float* k, const float* v,
                                             u16* Abf) {
    int z = blockIdx.z;
    const float* src = z == 0 ? q : z == 1 ? k : v;
    u16* dst = Abf + (size_t)z * 4194304;
    size_t i = ((size_t)blockIdx.x * 256 + threadIdx.x) * 8;
    float4 a = *(const float4*)(src + i);
    float4 b = *(const float4*)(src + i + 4);
    uint4v o;
    o[0] = cvtpk(a.x, a.y); o[1] = cvtpk(a.z, a.w);
    o[2] = cvtpk(b.x, b.y); o[3] = cvtpk(b.z, b.w);
    *(uint4v*)(dst + i) = o;
}

__global__ __launch_bounds__(256) void k_proj(const u16* Abf, const u16* Wt,
                                              const float* bq, const float* bk,
                                              const float* bv, u16* QKV) {
    int z = blockIdx.z;
    if (z == 2)
        gemm_body<1>(Abf + (size_t)2 * 4194304, Wt + (size_t)2 * 1048576, bv, 1.f,
                     QKV + (size_t)2 * 4194304);
    else if (z == 1)
        gemm_body<3>(Abf + (size_t)4194304, Wt + (size_t)1048576, bk, 1.f,
                     QKV + (size_t)4194304);
    else
        gemm_body<0>(Abf, Wt, bq, 0.125f, QKV);   // softmax scale folded into Q
}

// combine pre-normalized bf16 partials: Xc = x0*l0/(l0+l1) + x1*l1/(l0+l1)
__global__ __launch_bounds__(256) void k_combine(const u16* Xp, const float* Lp, u16* Xc) {
    size_t idx = (size_t)blockIdx.x * 256 + threadIdx.x;
    size_t e = idx * 8;
    int row = (int)(e >> 10), hh = ((int)e & 1023) >> 6;
    float l0 = Lp[(size_t)row * 16 + hh];
    float l1 = Lp[65536 + (size_t)row * 16 + hh];
    float s = 1.0f / (l0 + l1);
    float w0 = l0 * s, w1 = l1 * s;
    uint4v x0 = *(const uint4v*)(Xp + e);
    uint4v x1 = *(const uint4v*)(Xp + (size_t)4194304 + e);
    uint4v o;
    #pragma unroll
    for (int j = 0; j < 4; j++) {
        float a0 = bf2f(x0[j] & 0xffffu) * w0 + bf2f(x1[j] & 0xffffu) * w1;
        float a1 = bf2f(x0[j] >> 16)    * w0 + bf2f(x1[j] >> 16)    * w1;
        o[j] = cvtpk(a0, a1);
    }
    *(uint4v*)(Xc + e) = o;
}

__global__ __launch_bounds__(256) void k_gemm_out(const u16* Xc, const u16* Wt,
                                                  const float* bo, float* out) {
    gemm_body<2>(Xc, Wt, bo, 1.f, out);
}

// ---------------------------------------------------------------------------
// Causal flash attention, no-max softmax, K-split x2, heavy-first.
// grid (16, 32, 2), 256 thr; each wave owns 32 q rows, half the k-range.
// All K/V fragment loads are 1KB fully-coalesced reads from packed tiles.
// Partials: pre-normalized bf16 O + f32 lsum; combined by k_combine.
// ---------------------------------------------------------------------------
__global__ __launch_bounds__(256, 3) void k_attn(const u16* __restrict__ Qp,
                                                 const u16* __restrict__ Kp2,
                                                 const u16* __restrict__ Vp2,
                                                 u16* __restrict__ Xp, float* __restrict__ Lp) {
    const int bh = blockIdx.y, b = bh >> 4, h = bh & 15;
    const int t = threadIdx.x, lane = t & 63, w = t >> 6;
    const int lo = lane & 31, hi = lane >> 5;
    const int split = blockIdx.z;
    const int q0w = (int)(gridDim.x - 1 - blockIdx.x) * 128 + w * 32;   // heavy-first
    const u16* Qb = Qp + (size_t)(b * 2048) * 1024 + h * 64;
    const u16* Kb = Kp2 + (size_t)bh * 64 * 2048;
    const u16* Vb = Vp2 + (size_t)bh * 64 * 2048;

    short8 qf[4];
    #pragma unroll
    for (int c = 0; c < 4; c++)
        qf[c] = *(const short8*)(Qb + (size_t)(q0w + lo) * 1024 + c * 16 + hi * 8);

    f32x16 O0 = {}, O1 = {};
    float lsum = 0.f;
    const int qg = q0w + lo;
    const int nk = (q0w >> 5) + 1;       // causal k-tiles for this wave
    const int c0 = (nk + 1) >> 1;        // split 0 takes first c0 tiles
    const int kbeg = split ? (c0 << 5) : 0;
    const int kend = split ? (nk << 5) : (c0 << 5);

#define LOADKV(KF, VF, kk) do {                                                          \
        const u16* kt_ = Kb + (size_t)((kk) >> 5) * 2048;                                \
        const u16* vt_ = Vb + (size_t)((kk) >> 5) * 2048;                                \
        _Pragma("unroll")                                                                \
        for (int c = 0; c < 4; c++)                                                      \
            KF[c] = *(const short8*)(kt_ + c * 512 + lane * 8);                          \
        _Pragma("unroll")                                                                \
        for (int j = 0; j < 4; j++)                                                      \
            VF[j] = *(const short8*)(vt_ + j * 512 + lane * 8);                          \
    } while (0)

#define COMPUTE(KF, VF, kk) do {                                                          \
        f32x16 S = {};                                                                    \
        _Pragma("unroll")                                                                 \
        for (int c = 0; c < 4; c++)                                                       \
            S = __builtin_amdgcn_mfma_f32_32x32x16_bf16(KF[c], qf[c], S, 0, 0, 0);        \
        const bool diag = ((kk) == q0w);                                                  \
        _Pragma("unroll")                                                                 \
        for (int kc = 0; kc < 2; kc++) {                                                  \
            float p[8];                                                                   \
            _Pragma("unroll")                                                             \
            for (int j = 0; j < 8; j++) {                                                 \
                int r = kc * 8 + j;                                                       \
                float s = S[r];                                                           \
                if (diag) {                                                               \
                    int kg = (kk) + (r & 3) + 8 * (r >> 2) + 4 * hi;                      \
                    s = (kg <= qg) ? s : -1e30f;                                          \
                }                                                                         \
                p[j] = __expf(s);                                                         \
            }                                                                             \
            lsum += (((p[0] + p[1]) + (p[2] + p[3])) + ((p[4] + p[5]) + (p[6] + p[7])));  \
            u32 w0 = cvtpk(p[0], p[1]), w1 = cvtpk(p[2], p[3]);                           \
            u32 w2 = cvtpk(p[4], p[5]), w3 = cvtpk(p[6], p[7]);                           \
            auto r0 = __builtin_amdgcn_permlane32_swap(w0, w2, false, false);             \
            auto r1 = __builtin_amdgcn_permlane32_swap(w1, w3, false, false);             \
            uint4v fw; fw[0] = r0[0]; fw[1] = r1[0]; fw[2] = r0[1]; fw[3] = r1[1];        \
            short8 pf = __builtin_bit_cast(short8, fw);                                   \
            O0 = __builtin_amdgcn_mfma_f32_32x32x16_bf16(pf, VF[kc * 2 + 0], O0, 0, 0, 0);\
            O1 = __builtin_amdgcn_mfma_f32_32x32x16_bf16(pf, VF[kc * 2 + 1], O1, 0, 0, 0);\
        }                                                                                 \
    } while (0)

    if (kbeg < kend) {
        short8 kf0[4], vf0[4], kf1[4], vf1[4];
        LOADKV(kf0, vf0, kbeg);
        int k0 = kbeg;
        while (true) {
            if (k0 + 32 < kend) LOADKV(kf1, vf1, k0 + 32);
            COMPUTE(kf0, vf0, k0);
            k0 += 32;
            if (k0 >= kend) break;
            if (k0 + 32 < kend) LOADKV(kf0, vf0, k0 + 32);
            COMPUTE(kf1, vf1, k0);
            k0 += 32;
            if (k0 >= kend) break;
        }
    }
#undef LOADKV
#undef COMPUTE

    float ltot = lsum + __shfl_xor(lsum, 32, 64);
    u16* Xb = Xp + (size_t)split * 4194304;
    #pragma unroll
    for (int r = 0; r < 16; r++) {
        int qr = (r & 3) + 8 * (r >> 2) + 4 * hi;
        // normalizer belongs to q-row qr, which lives in lane qr (and qr+32)
        float lt = __shfl(ltot, qr, 64);
        float linv = lt > 0.f ? 1.f / lt : 0.f;
        size_t rowb = (size_t)(b * 2048 + q0w + qr) * 1024 + h * 64;
        Xb[rowb + lo]      = f2bf(O0[r] * linv);
        Xb[rowb + 32 + lo] = f2bf(O1[r] * linv);
    }
    if (hi == 0)
        Lp[(size_t)split * 65536 + (size_t)(b * 2048 + q0w + lo) * 16 + h] = ltot;
}

extern "C" void kernel_launch(void* const* d_in, const int* in_sizes, int n_in,
                              void* d_out, int out_size, void* d_ws, size_t ws_size,
                              hipStream_t stream) {
    (void)in_sizes; (void)n_in; (void)out_size; (void)ws_size;
    const float* q  = (const float*)d_in[0];
    const float* k  = (const float*)d_in[1];
    const float* v  = (const float*)d_in[2];
    const float* Wq = (const float*)d_in[3];
    const float* bq = (const float*)d_in[4];
    const float* Wk = (const float*)d_in[5];
    const float* bk = (const float*)d_in[6];
    const float* Wv = (const float*)d_in[7];
    const float* bv = (const float*)d_in[8];
    const float* Wo = (const float*)d_in[9];
    const float* bo = (const float*)d_in[10];

    // workspace layout (u16 units):
    //   [0, 4M)       Wt   : 4 x 1024x1024 bf16            (8 MB)
    //   [4M, 16.5M)   QKV  : Q rm, K packed, V packed      (24 MB)
    //   [16.5M, 29M)  Abf  : q,k,v bf16 (dead after proj)  (24 MB)
    //                  reused: Xp = Abf (2 segs), Xc = Abf+2 segs
    //   then Lp: 2 x 4096x16 f32                           (512 KB)
    u16*   Wt  = (u16*)d_ws;
    u16*   QKV = Wt + (size_t)4 * 1048576;
    u16*   Abf = QKV + (size_t)3 * 4194304;
    u16*   Xp  = Abf;                         // reuse (Abf dead after k_proj)
    u16*   Xc  = Abf + (size_t)2 * 4194304;
    float* Lp  = (float*)(Abf + (size_t)3 * 4194304);

    k_transw<<<dim3(32, 32, 4), dim3(32, 8), 0, stream>>>(Wq, Wk, Wv, Wo, Wt);
    k_cvt<<<dim3(2048, 1, 3), 256, 0, stream>>>(q, k, v, Abf);
    k_proj<<<dim3(8, 32, 3), 256, 0, stream>>>(Abf, Wt, bq, bk, bv, QKV);
    k_attn<<<dim3(16, 32, 2), 256, 0, stream>>>(QKV, QKV + (size_t)4194304,
                                                QKV + (size_t)2 * 4194304, Xp, Lp);
    k_combine<<<2048, 256, 0, stream>>>(Xp, Lp, Xc);
    k_gemm_out<<<dim3(8, 32), 256, 0, stream>>>(Xc, Wt + (size_t)3 * 1048576,
                                                bo, (float*)d_out);
}

// Round 6
// 134.013 us; speedup vs baseline: 1.8490x; 1.0400x over previous
//
#include <hip/hip_runtime.h>

typedef unsigned short u16;
typedef unsigned int   u32;
typedef __attribute__((ext_vector_type(8)))  short short8;
typedef __attribute__((ext_vector_type(4)))  float f32x4;
typedef __attribute__((ext_vector_type(16))) float f32x16;
typedef __attribute__((ext_vector_type(2)))  u32 uint2v;
typedef __attribute__((ext_vector_type(4)))  u32 uint4v;

#define DEV __device__ __forceinline__

DEV u16 f2bf(float f) {
    u32 u = __builtin_bit_cast(u32, f);
    return (u16)((u + 0x7fffu + ((u >> 16) & 1u)) >> 16);
}
DEV float bf2f(u32 u) { return __builtin_bit_cast(float, u << 16); }
DEV u32 cvtpk(float a, float b) {
    u32 r;
    asm("v_cvt_pk_bf16_f32 %0, %1, %2" : "=v"(r) : "v"(a), "v"(b));
    return r;
}
typedef const __attribute__((address_space(1))) u32 g_u32;
typedef __attribute__((address_space(3))) u32 l_u32;
DEV void gload16(const u16* g, u16* l) {
    __builtin_amdgcn_global_load_lds((g_u32*)g, (l_u32*)l, 16, 0, 0);
}

// ---------------------------------------------------------------------------
// Packed K layout (per bh, per 32-token tile, 4KB): elem index
//   ((c*2+hi)*32 + lo)*8 + e  holds  K[t=tblk*32+lo][d=c*16+hi*8+e]
// => attn fragment load kf[c] = 16B at tile + (c*64+lane)*16B, fully linear.
// Packed V layout (per bh, per 32-token tile, 4KB): elem index
//   ((kc*2+c2)*64 + hi*32 + lo)*8 + e holds V[t=tblk*32+kc*16+hi*8+e][d=c2*32+lo]
// => attn fragment load vf[kc*2+c2] = 16B at tile + ((kc*2+c2)*64+lane)*16B.
// ---------------------------------------------------------------------------

// GEMM: C[4096,1024] = A[4096,1024](bf16) @ Wt[n][k](bf16) + bias.
// 128x128 tile, BK=32, 256 thr (4 waves 2x2), 16x16x32 MFMA.
// Both A and B staged via global_load_lds width-16 (m97 path).
// OMODE 0: bf16 row-major (*oscale); 1: packed-V tiles; 2: f32 row-major;
//   3: packed-K tiles.
template<int OMODE>
DEV void gemm_body(const u16* __restrict__ A_, const u16* __restrict__ Bt,
                   const float* __restrict__ bias, float oscale, void* C_) {
    constexpr int Kd = 1024;
    const int m0 = blockIdx.y * 128, n0 = blockIdx.x * 128;
    const int t = threadIdx.x, lane = t & 63, w = t >> 6;
    const int wm = w >> 1, wn = w & 1;
    const int l15 = lane & 15, l4 = lane >> 4;
    __shared__ __align__(16) u16 As[128 * 32];
    __shared__ __align__(16) u16 Bs[128 * 32];
    f32x4 acc[4][4] = {};

    for (int k0 = 0; k0 < Kd; k0 += 32) {
        #pragma unroll
        for (int rnd = 0; rnd < 2; rnd++) {
            int cc = rnd * 256 + t, row = cc >> 2, slot = cc & 3;
            gload16(Bt + (size_t)(n0 + row) * Kd + k0 + slot * 8, Bs + cc * 8);
            gload16(A_ + (size_t)(m0 + row) * Kd + k0 + slot * 8, As + cc * 8);
        }
        __syncthreads();
        short8 af[4], bfr[4];
        #pragma unroll
        for (int i = 0; i < 4; i++) {
            af[i]  = *(const short8*)(As + (wm * 64 + i * 16 + l15) * 32 + l4 * 8);
            bfr[i] = *(const short8*)(Bs + (wn * 64 + i * 16 + l15) * 32 + l4 * 8);
        }
        #pragma unroll
        for (int i = 0; i < 4; i++)
            #pragma unroll
            for (int j = 0; j < 4; j++)
                acc[i][j] = __builtin_amdgcn_mfma_f32_16x16x32_bf16(af[i], bfr[j], acc[i][j], 0, 0, 0);
        __syncthreads();
    }

    #pragma unroll
    for (int i = 0; i < 4; i++) {
        #pragma unroll
        for (int j = 0; j < 4; j++) {
            int col = n0 + wn * 64 + j * 16 + l15;
            int mb  = m0 + wm * 64 + i * 16 + l4 * 4;
            float bv = bias[col];
            if (OMODE == 2) {
                float* C = (float*)C_;
                #pragma unroll
                for (int r = 0; r < 4; r++)
                    C[(size_t)(mb + r) * 1024 + col] = acc[i][j][r] + bv;
            } else if (OMODE == 0) {
                u16* C = (u16*)C_;
                #pragma unroll
                for (int r = 0; r < 4; r++)
                    C[(size_t)(mb + r) * 1024 + col] = f2bf((acc[i][j][r] + bv) * oscale);
            } else if (OMODE == 3) {
                // packed K tiles
                u16* C = (u16*)C_;
                int hh = col >> 6, dd = col & 63;
                int bb = mb >> 11, tt = mb & 2047;
                size_t tile = ((size_t)(bb * 16 + hh) * 64 + (tt >> 5)) * 2048;
                int c = dd >> 4, hi2 = (dd >> 3) & 1, e = dd & 7;
                int lob = tt & 31;
                #pragma unroll
                for (int r = 0; r < 4; r++)
                    C[tile + (size_t)((c * 2 + hi2) * 32 + lob + r) * 8 + e] =
                        f2bf(acc[i][j][r] + bv);
            } else {
                // packed V tiles: 4 consecutive tokens are contiguous elems
                u16* C = (u16*)C_;
                int hh = col >> 6, dd = col & 63;
                int bb = mb >> 11, tt = mb & 2047;
                size_t tile = ((size_t)(bb * 16 + hh) * 64 + (tt >> 5)) * 2048;
                int tin = tt & 31, kc = tin >> 4, hi2 = (tin >> 3) & 1, e0 = tin & 7;
                int c2 = dd >> 5, lo2 = dd & 31;
                size_t off = tile + (size_t)((kc * 2 + c2) * 64 + hi2 * 32 + lo2) * 8 + e0;
                uint2v pp;
                pp[0] = cvtpk(acc[i][j][0] + bv, acc[i][j][1] + bv);
                pp[1] = cvtpk(acc[i][j][2] + bv, acc[i][j][3] + bv);
                *(uint2v*)(C + off) = pp;
            }
        }
    }
}

// weights: W[k][n] f32 -> Wt[n][k] bf16
__global__ __launch_bounds__(256) void k_transw(const float* Wq, const float* Wk,
                                                const float* Wv, const float* Wo, u16* Wt) {
    int z = blockIdx.z;
    const float* W = z == 0 ? Wq : z == 1 ? Wk : z == 2 ? Wv : Wo;
    u16* O = Wt + (size_t)z * 1048576;
    __shared__ float tile[32][33];
    int n0 = blockIdx.x * 32, k0 = blockIdx.y * 32;
    int tx = threadIdx.x, ty = threadIdx.y;
    #pragma unroll
    for (int i = 0; i < 32; i += 8) tile[ty + i][tx] = W[(size_t)(k0 + ty + i) * 1024 + n0 + tx];
    __syncthreads();
    #pragma unroll
    for (int i = 0; i < 32; i += 8) O[(size_t)(n0 + ty + i) * 1024 + k0 + tx] = f2bf(tile[tx][ty + i]);
}

// q,k,v f32 -> bf16, fully coalesced, 8 elems/thread, exact coverage
__global__ __launch_bounds__(256) void k_cvt(const float* q, const float* k, const float* v,
                                             u16* Abf) {
    int z = blockIdx.z;
    const float* src = z == 0 ? q : z == 1 ? k : v;
    u16* dst = Abf + (size_t)z * 4194304;
    size_t i = ((size_t)blockIdx.x * 256 + threadIdx.x) * 8;
    float4 a = *(const float4*)(src + i);
    float4 b = *(const float4*)(src + i + 4);
    uint4v o;
    o[0] = cvtpk(a.x, a.y); o[1] = cvtpk(a.z, a.w);
    o[2] = cvtpk(b.x, b.y); o[3] = cvtpk(b.z, b.w);
    *(uint4v*)(dst + i) = o;
}

__global__ __launch_bounds__(256) void k_proj(const u16* Abf, const u16* Wt,
                                              const float* bq, const float* bk,
                                              const float* bv, u16* QKV) {
    int z = blockIdx.z;
    if (z == 2)
        gemm_body<1>(Abf + (size_t)2 * 4194304, Wt + (size_t)2 * 1048576, bv, 1.f,
                     QKV + (size_t)2 * 4194304);
    else if (z == 1)
        gemm_body<3>(Abf + (size_t)4194304, Wt + (size_t)1048576, bk, 1.f,
                     QKV + (size_t)4194304);
    else
        gemm_body<0>(Abf, Wt, bq, 0.125f, QKV);   // softmax scale folded into Q
}

__global__ __launch_bounds__(256) void k_gemm_out(const u16* Xc, const u16* Wt,
                                                  const float* bo, float* out) {
    gemm_body<2>(Xc, Wt, bo, 1.f, out);
}

// ---------------------------------------------------------------------------
// Causal flash attention, zigzag-paired, no-max softmax, no K-split.
// grid (8, 32), 256 thr. Wave w of block x owns PAIR p = x*4+w: q-tiles
// (p, 63-p) -> exactly 65 k-tile computations per wave, perfectly balanced.
// The two chains share K/V loads on k < p+1 (two independent MFMA chains per
// load = free ILP). Output written directly, normalized, bf16. No partials.
// ---------------------------------------------------------------------------
__global__ __launch_bounds__(256, 1) void k_attn(const u16* __restrict__ Qp,
                                                 const u16* __restrict__ Kp2,
                                                 const u16* __restrict__ Vp2,
                                                 u16* __restrict__ Xc) {
    const int bh = blockIdx.y, b = bh >> 4, h = bh & 15;
    const int t = threadIdx.x, lane = t & 63, w = t >> 6;
    const int lo = lane & 31, hi = lane >> 5;
    const int p = blockIdx.x * 4 + w;          // pair index 0..31
    const int q0a = p * 32, q0b = (63 - p) * 32;
    const int nka = p + 1, nkb = 64 - p;       // k-tiles per chain (nkb > nka)
    const u16* Qb = Qp + (size_t)(b * 2048) * 1024 + h * 64;
    const u16* Kb = Kp2 + (size_t)bh * 64 * 2048;
    const u16* Vb = Vp2 + (size_t)bh * 64 * 2048;

    short8 qfa[4], qfb[4];
    #pragma unroll
    for (int c = 0; c < 4; c++) {
        qfa[c] = *(const short8*)(Qb + (size_t)(q0a + lo) * 1024 + c * 16 + hi * 8);
        qfb[c] = *(const short8*)(Qb + (size_t)(q0b + lo) * 1024 + c * 16 + hi * 8);
    }

    f32x16 Oa0 = {}, Oa1 = {}, Ob0 = {}, Ob1 = {};
    float lsa = 0.f, lsb = 0.f;
    const int qga = q0a + lo, qgb = q0b + lo;

#define LOADKV(KF, VF, kt) do {                                                          \
        const u16* kt_ = Kb + (size_t)(kt) * 2048;                                       \
        const u16* vt_ = Vb + (size_t)(kt) * 2048;                                       \
        _Pragma("unroll")                                                                \
        for (int c = 0; c < 4; c++)                                                      \
            KF[c] = *(const short8*)(kt_ + c * 512 + lane * 8);                          \
        _Pragma("unroll")                                                                \
        for (int j = 0; j < 4; j++)                                                      \
            VF[j] = *(const short8*)(vt_ + j * 512 + lane * 8);                          \
    } while (0)

    // softmax + PV for one chain's S tile
#define SMPV(S, O0, O1, lsum, diag, qg, kt, VF) do {                                      \
        _Pragma("unroll")                                                                 \
        for (int kc = 0; kc < 2; kc++) {                                                  \
            float pv[8];                                                                  \
            _Pragma("unroll")                                                             \
            for (int j = 0; j < 8; j++) {                                                 \
                int r = kc * 8 + j;                                                       \
                float s = S[r];                                                           \
                if (diag) {                                                               \
                    int kg = (kt) * 32 + (r & 3) + 8 * (r >> 2) + 4 * hi;                 \
                    s = (kg <= (qg)) ? s : -1e30f;                                        \
                }                                                                         \
                pv[j] = __expf(s);                                                        \
            }                                                                             \
            lsum += (((pv[0] + pv[1]) + (pv[2] + pv[3])) +                                \
                     ((pv[4] + pv[5]) + (pv[6] + pv[7])));                                \
            u32 w0 = cvtpk(pv[0], pv[1]), w1 = cvtpk(pv[2], pv[3]);                       \
            u32 w2 = cvtpk(pv[4], pv[5]), w3 = cvtpk(pv[6], pv[7]);                       \
            auto r0 = __builtin_amdgcn_permlane32_swap(w0, w2, false, false);             \
            auto r1 = __builtin_amdgcn_permlane32_swap(w1, w3, false, false);             \
            uint4v fw; fw[0] = r0[0]; fw[1] = r1[0]; fw[2] = r0[1]; fw[3] = r1[1];        \
            short8 pf = __builtin_bit_cast(short8, fw);                                   \
            O0 = __builtin_amdgcn_mfma_f32_32x32x16_bf16(pf, VF[kc * 2 + 0], O0, 0, 0, 0);\
            O1 = __builtin_amdgcn_mfma_f32_32x32x16_bf16(pf, VF[kc * 2 + 1], O1, 0, 0, 0);\
        }                                                                                 \
    } while (0)

    // one k-tile step: chain B always, chain A while kt < nka (shared K/V)
#define STEP(KF, VF, kt) do {                                                             \
        const bool doA = (kt) < nka;                                                      \
        f32x16 Sb = {}, Sa = {};                                                          \
        _Pragma("unroll")                                                                 \
        for (int c = 0; c < 4; c++)                                                       \
            Sb = __builtin_amdgcn_mfma_f32_32x32x16_bf16(KF[c], qfb[c], Sb, 0, 0, 0);     \
        if (doA) {                                                                        \
            _Pragma("unroll")                                                             \
            for (int c = 0; c < 4; c++)                                                   \
                Sa = __builtin_amdgcn_mfma_f32_32x32x16_bf16(KF[c], qfa[c], Sa, 0, 0, 0); \
            SMPV(Sa, Oa0, Oa1, lsa, (kt) == nka - 1, qga, kt, VF);                        \
        }                                                                                 \
        SMPV(Sb, Ob0, Ob1, lsb, (kt) == nkb - 1, qgb, kt, VF);                            \
    } while (0)

    {
        short8 kf0[4], vf0[4], kf1[4], vf1[4];
        LOADKV(kf0, vf0, 0);
        int kt = 0;
        while (true) {
            if (kt + 1 < nkb) LOADKV(kf1, vf1, kt + 1);
            STEP(kf0, vf0, kt);
            ++kt;
            if (kt >= nkb) break;
            if (kt + 1 < nkb) LOADKV(kf0, vf0, kt + 1);
            STEP(kf1, vf1, kt);
            ++kt;
            if (kt >= nkb) break;
        }
    }
#undef LOADKV
#undef SMPV
#undef STEP

#define EPI(O0, O1, lsum, q0) do {                                                        \
        float ltot = (lsum) + __shfl_xor((lsum), 32, 64);                                 \
        _Pragma("unroll")                                                                 \
        for (int r = 0; r < 16; r++) {                                                    \
            int qr = (r & 3) + 8 * (r >> 2) + 4 * hi;                                     \
            float lt = __shfl(ltot, qr, 64);                                              \
            float linv = lt > 0.f ? 1.f / lt : 0.f;                                       \
            size_t rowb = (size_t)(b * 2048 + (q0) + qr) * 1024 + h * 64;                 \
            Xc[rowb + lo]      = f2bf(O0[r] * linv);                                      \
            Xc[rowb + 32 + lo] = f2bf(O1[r] * linv);                                      \
        }                                                                                 \
    } while (0)

    EPI(Oa0, Oa1, lsa, q0a);
    EPI(Ob0, Ob1, lsb, q0b);
#undef EPI
}

extern "C" void kernel_launch(void* const* d_in, const int* in_sizes, int n_in,
                              void* d_out, int out_size, void* d_ws, size_t ws_size,
                              hipStream_t stream) {
    (void)in_sizes; (void)n_in; (void)out_size; (void)ws_size;
    const float* q  = (const float*)d_in[0];
    const float* k  = (const float*)d_in[1];
    const float* v  = (const float*)d_in[2];
    const float* Wq = (const float*)d_in[3];
    const float* bq = (const float*)d_in[4];
    const float* Wk = (const float*)d_in[5];
    const float* bk = (const float*)d_in[6];
    const float* Wv = (const float*)d_in[7];
    const float* bv = (const float*)d_in[8];
    const float* Wo = (const float*)d_in[9];
    const float* bo = (const float*)d_in[10];

    // workspace layout (u16 units):
    //   [0, 4M)     Wt  : 4 x 1024x1024 bf16                 (8 MB)
    //   [4M, 16M)   QKV : Q row-major, K packed, V packed    (24 MB)
    //   [16M, 28M)  Abf : q,k,v bf16 (dead after k_proj)     (24 MB)
    //               reused: Xc = Abf[0:4M)
    u16* Wt  = (u16*)d_ws;
    u16* QKV = Wt + (size_t)4 * 1048576;
    u16* Abf = QKV + (size_t)3 * 4194304;
    u16* Xc  = Abf;                           // reuse (Abf dead after k_proj)

    k_transw<<<dim3(32, 32, 4), dim3(32, 8), 0, stream>>>(Wq, Wk, Wv, Wo, Wt);
    k_cvt<<<dim3(2048, 1, 3), 256, 0, stream>>>(q, k, v, Abf);
    k_proj<<<dim3(8, 32, 3), 256, 0, stream>>>(Abf, Wt, bq, bk, bv, QKV);
    k_attn<<<dim3(8, 32), 256, 0, stream>>>(QKV, QKV + (size_t)4194304,
                                            QKV + (size_t)2 * 4194304, Xc);
    k_gemm_out<<<dim3(8, 32), 256, 0, stream>>>(Xc, Wt + (size_t)3 * 1048576,
                                                bo, (float*)d_out);
}